// Round 4
// baseline (314.076 us; speedup 1.0000x reference)
//
#include <hip/hip_runtime.h>

// GaussianKernel: out[b,n,m] = exp(inv2s * (||Q[b,n]||^2 + ||KV[b,:,m]||^2 - 2*Q[b,n]·KV[b,:,m]))
// B=16, N=2048, M=2048, D=128, fp32 in/out.
//
// R5 (on R4's swapped-operand MFMA + K-split + 3 blocks/CU):
//  - XCD-chunked block swizzle (bijective, 256%8==0): each XCD owns 2 n-tiles
//    x 16 m-tiles -> A/B tiles resident in the LOCAL L2 (~580KB), stage phase
//    becomes local-L2 hits instead of 8x L3 refetch.
//  - Non-temporal output stores: 268MB write-once stream no longer churns the
//    4MB/XCD L2 holding the staged fp16 tiles.
//  - prep_kv: float2 transpose (lane covers 2 adjacent m-cols) -> 512B/instr
//    coalesced reads, half the read instructions. Same per-element order ->
//    bit-identical results.

#define B_  16
#define N_  2048
#define M_  2048
#define D_  128

typedef _Float16 half8 __attribute__((ext_vector_type(8)));
typedef float    f32x4 __attribute__((ext_vector_type(4)));

// ------------------------------------------------------------ fused prep ----
// blocks [0,256):      KV[b,k,m] -> KTh[b,m,k] fp16 + Ksq[b,m]
//                      block = 128 cols x 128 k; wave wv: k in [wv*32,wv*32+32);
//                      lane covers cols (2*ln, 2*ln+1) via float2 loads.
// blocks [256,256+8192): Q -> Qh fp16 + Qsq (4 rows per block)
__global__ __launch_bounds__(256) void prep_all(const float* __restrict__ Q,
                                                const float* __restrict__ KV,
                                                _Float16* __restrict__ Qh,
                                                float* __restrict__ Qsq,
                                                _Float16* __restrict__ KTh,
                                                float* __restrict__ Ksq) {
    const int tid = threadIdx.x;
    if (blockIdx.x < 256) {
        __shared__ float part[4][128];
        const int bx = blockIdx.x;
        const int b  = bx >> 4;             // 16 blocks per batch
        const int m0 = (bx & 15) << 7;      // 128 columns per block
        const int wv = tid >> 6;            // k-chunk: [wv*32, wv*32+32)
        const int ln = tid & 63;
        const int c0 = m0 + ln * 2;
        const float* src = KV + (size_t)b * D_ * M_ + (size_t)(wv * 32) * M_ + c0;
        float sq0 = 0.f, sq1 = 0.f;
        union { _Float16 h[32]; int4 v[4]; } e, o;
        #pragma unroll
        for (int j = 0; j < 32; ++j) {
            const float2 v = *reinterpret_cast<const float2*>(src + (size_t)j * M_);
            sq0 = fmaf(v.x, v.x, sq0);
            sq1 = fmaf(v.y, v.y, sq1);
            e.h[j] = (_Float16)v.x;
            o.h[j] = (_Float16)v.y;
        }
        _Float16* d0 = KTh + ((size_t)b * M_ + c0) * D_ + wv * 32;
        #pragma unroll
        for (int j = 0; j < 4; ++j) reinterpret_cast<int4*>(d0)[j] = e.v[j];
        _Float16* d1 = d0 + D_;
        #pragma unroll
        for (int j = 0; j < 4; ++j) reinterpret_cast<int4*>(d1)[j] = o.v[j];
        part[wv][ln * 2]     = sq0;
        part[wv][ln * 2 + 1] = sq1;
        __syncthreads();
        if (tid < 128)
            Ksq[(size_t)b * M_ + m0 + tid] =
                part[0][tid] + part[1][tid] + part[2][tid] + part[3][tid];
    } else {
        const int row  = (blockIdx.x - 256) * 4 + (tid >> 6);
        const int lane = tid & 63;
        const float2 v = reinterpret_cast<const float2*>(Q + (size_t)row * D_)[lane];
        float sq = v.x * v.x + v.y * v.y;
        union { _Float16 h[2]; unsigned int u; } pk;
        pk.h[0] = (_Float16)v.x;
        pk.h[1] = (_Float16)v.y;
        reinterpret_cast<unsigned int*>(Qh + (size_t)row * D_)[lane] = pk.u;
        #pragma unroll
        for (int off = 32; off > 0; off >>= 1) sq += __shfl_down(sq, off, 64);
        if (lane == 0) Qsq[row] = sq;
    }
}

// ------------------------------------------------------------------ GEMM ----
__global__ __launch_bounds__(256, 3) void gauss_gemm(
    const _Float16* __restrict__ Qh, const _Float16* __restrict__ KTh,
    const float* __restrict__ Qsq,  const float* __restrict__ Ksq,
    const float* __restrict__ ls,   float* __restrict__ out) {
    __shared__ __align__(16) _Float16 Ash[128 * 64];   // 16 KB (one K-half of A)
    __shared__ __align__(16) _Float16 Bsh[128 * 64];   // 16 KB (one K-half of B)

    const int b    = blockIdx.y;
    const int bx   = blockIdx.x;
    // XCD-chunked swizzle: hw round-robins consecutive bx across the 8 XCDs;
    // remap so XCD k owns logical blocks [k*32, k*32+32) = 2 n-tiles x 16 m.
    const int lx   = ((bx & 7) << 5) | (bx >> 3);
    const int n0   = (lx >> 4) << 7;
    const int m0   = (lx & 15) << 7;
    const int tid  = threadIdx.x;
    const int wave = tid >> 6;
    const int lane = tid & 63;

    const _Float16* Ag = Qh  + ((size_t)b * N_ + n0) * D_;
    const _Float16* Bg = KTh + ((size_t)b * M_ + m0) * D_;

    // Staging: granule = 16B (8 halves); swizzle applied on the GLOBAL address
    // (logical granule gc ^ (r&7)); LDS dst stays linear wave-uniform.
    int goff[4];
    #pragma unroll
    for (int j = 0; j < 4; ++j) {
        const int gi = j * 256 + tid;
        const int r  = gi >> 3;
        const int gc = gi & 7;
        goff[j] = r * D_ + ((gc ^ (r & 7)) << 3);
    }
    const int dbase = wave * 512;

    auto STAGE = [&](int h) {
        #pragma unroll
        for (int j = 0; j < 4; ++j) {
            __builtin_amdgcn_global_load_lds(
                (const __attribute__((address_space(1))) unsigned int*)(Ag + h * 64 + goff[j]),
                (__attribute__((address_space(3))) unsigned int*)(&Ash[j * 2048 + dbase]), 16, 0, 0);
            __builtin_amdgcn_global_load_lds(
                (const __attribute__((address_space(1))) unsigned int*)(Bg + h * 64 + goff[j]),
                (__attribute__((address_space(3))) unsigned int*)(&Bsh[j * 2048 + dbase]), 16, 0, 0);
        }
    };

    const int wr  = (wave >> 1) << 6;
    const int wc  = (wave & 1) << 6;
    const int lm  = lane & 15;
    const int kq  = lane >> 4;
    const int fsw = lm & 7;                // read-side XOR (frag row&7 == lm&7)

    auto READ = [&](half8 af[2][4], half8 bf[2][4]) {
        #pragma unroll
        for (int s = 0; s < 2; ++s) {
            const int pc = ((((s << 2) + kq) ^ fsw) << 3);
            #pragma unroll
            for (int rr = 0; rr < 4; ++rr)
                af[s][rr] = *reinterpret_cast<const half8*>(
                    &Ash[(wr + rr * 16 + lm) * 64 + pc]);
            #pragma unroll
            for (int cc = 0; cc < 4; ++cc)
                bf[s][cc] = *reinterpret_cast<const half8*>(
                    &Bsh[(wc + cc * 16 + lm) * 64 + pc]);
        }
    };

    f32x4 acc[4][4] = {};
    // SWAPPED operands: lane's 4 regs = 4 consecutive m (bit-identical math).
    auto MFMA = [&](half8 af[2][4], half8 bf[2][4]) {
        #pragma unroll
        for (int s = 0; s < 2; ++s)
            #pragma unroll
            for (int rr = 0; rr < 4; ++rr)
                #pragma unroll
                for (int cc = 0; cc < 4; ++cc)
                    acc[rr][cc] = __builtin_amdgcn_mfma_f32_16x16x32_f16(
                        bf[s][cc], af[s][rr], acc[rr][cc], 0, 0, 0);
    };

    STAGE(0);
    __syncthreads();                       // h0 in LDS

    half8 a0[2][4], b0[2][4];
    READ(a0, b0);                          // all h0 frags -> regs
    __syncthreads();                       // LDS reusable

    STAGE(1);                              // h1 in flight ...
    MFMA(a0, b0);                          // ... hidden under h0's 32 MFMAs
    __syncthreads();                       // h1 in LDS

    half8 a1[2][4], b1[2][4];
    READ(a1, b1);
    MFMA(a1, b1);

    // ---- epilogue: exp + NON-TEMPORAL f32x4 stores --------------------------
    const float inv2s = -0.5f * __expf(-2.0f * ls[0]);
    const float cm2   = -2.0f * inv2s;
    const float* qsq = Qsq + (size_t)b * N_ + n0;
    const float* ksq = Ksq + (size_t)b * M_ + m0;

    float qv[4];
    #pragma unroll
    for (int rr = 0; rr < 4; ++rr) qv[rr] = inv2s * qsq[wr + rr * 16 + lm];
    f32x4 kv[4];
    #pragma unroll
    for (int cc = 0; cc < 4; ++cc) {
        const f32x4 kr = *reinterpret_cast<const f32x4*>(&ksq[wc + cc * 16 + (kq << 2)]);
        #pragma unroll
        for (int e = 0; e < 4; ++e) kv[cc][e] = inv2s * kr[e];
    }

    float* Cb = out + ((size_t)b * N_ + n0 + wr + lm) * M_ + m0 + wc + (kq << 2);
    #pragma unroll
    for (int rr = 0; rr < 4; ++rr) {
        float* p = Cb + (size_t)(rr * 16) * M_;
        #pragma unroll
        for (int cc = 0; cc < 4; ++cc) {
            f32x4 v;
            #pragma unroll
            for (int e = 0; e < 4; ++e)
                v[e] = __expf(fmaf(cm2, acc[rr][cc][e], qv[rr] + kv[cc][e]));
            __builtin_nontemporal_store(v, reinterpret_cast<f32x4*>(p + cc * 16));
        }
    }
}

// ---------------------------------------------------------------- launch ----
extern "C" void kernel_launch(void* const* d_in, const int* in_sizes, int n_in,
                              void* d_out, int out_size, void* d_ws, size_t ws_size,
                              hipStream_t stream) {
    const float* Q  = (const float*)d_in[0];
    const float* KV = (const float*)d_in[1];
    const float* ls = (const float*)d_in[2];
    float* out = (float*)d_out;

    char* ws = (char*)d_ws;
    _Float16* Qh  = (_Float16*)ws;
    _Float16* KTh = (_Float16*)(ws + (size_t)8 * 1024 * 1024);
    float*    Qsq = (float*)(ws + (size_t)16 * 1024 * 1024);
    float*    Ksq = (float*)(ws + (size_t)16 * 1024 * 1024 + 128 * 1024);

    prep_all<<<dim3(256 + B_ * N_ / 4), 256, 0, stream>>>(Q, KV, Qh, Qsq, KTh, Ksq);
    gauss_gemm<<<dim3(256, B_), 256, 0, stream>>>(Qh, KTh, Qsq, Ksq, ls, out);
}